// Round 1
// baseline (799.106 us; speedup 1.0000x reference)
//
#include <hip/hip_runtime.h>
#include <stdint.h>

// DenseGGNN on MI355X. Strategy: bf16 MFMA everywhere with hi/lo split-precision.
//   adj entries are {0,1} = exact in bf16 -> adjT GEMM uses 2 products (B hi/lo).
//   All other GEMMs use 3 products (ahi*bhi + ahi*blo + alo*bhi): residual ~2^-16 rel.
// Buffers in ws (~170 MB): h f32 + h hi/lo, hwT hi/lo (transposed for K2 B-staging),
//   m hi/lo, gx/gh f32, split weights.

#define NB 32
#define NN 1024
#define NC 128
#define NL 4
#define MTOT (NB * NN)   // 32768

#define KT 64
#define PITCH 72         // 144B row stride: 16B aligned, bank step 4 -> <=2-way conflicts

typedef __attribute__((ext_vector_type(8))) short s16x8;
typedef __attribute__((ext_vector_type(4))) float f32x4;
typedef unsigned short U16;
typedef unsigned int U32;

__device__ __forceinline__ U16 f2bf(float f) {
    union { float f; U32 u; } v; v.f = f;
    return (U16)((v.u + 0x7FFFu + ((v.u >> 16) & 1u)) >> 16);  // RNE
}
__device__ __forceinline__ float bf2f(U16 h) {
    union { U32 u; float f; } v; v.u = ((U32)h) << 16;
    return v.f;
}
__device__ __forceinline__ void splitbf(float x, U16& hi, U16& lo) {
    hi = f2bf(x);
    lo = f2bf(x - bf2f(hi));
}

// ---------------- shared-memory tiles ----------------
struct __align__(16) Smem3 {               // 3-product kernels: A hi/lo + B hi/lo
    union {
        struct { U16 A[2][128 * PITCH]; U16 B[2][128 * PITCH]; } s;   // 73728 B
        float bounce[128 * 129];                                      // 66048 B
    };
};
struct __align__(16) Smem2 {               // adj kernel: A single + B hi/lo
    union {
        struct { U16 A[128 * PITCH]; U16 B[2][128 * PITCH]; } s;      // 55296 B
        float bounce[128 * 129];                                      // 66048 B
    };
};

// ---------------- K1: hw = h @ W  (3-product), writes hwT[b][d][j] hi/lo ----------------
__global__ __launch_bounds__(256, 2) void k_hw(
    const U16* __restrict__ Ahi, const U16* __restrict__ Alo,   // h   [MTOT][128]
    const U16* __restrict__ Bhi, const U16* __restrict__ Blo,   // wT  [128][128] (layer slice)
    U16* __restrict__ Ohi, U16* __restrict__ Olo)               // hwT [NB][128][1024]
{
    __shared__ Smem3 sm;
    const int tid = threadIdx.x;
    const int lane = tid & 63, wv = tid >> 6;
    const int wr = (wv & 1) * 64, wc = (wv >> 1) * 64;
    const int lm = lane & 15, lk8 = (lane >> 4) * 8;
    const int m0 = blockIdx.x * 128;

    f32x4 acc[4][4] = {};

    for (int kc = 0; kc < 128; kc += KT) {
#pragma unroll
        for (int t = 0; t < 4; ++t) {                 // A: 1024 vec8 per buffer
            int i = tid + t * 256; int r = i >> 3, v = (i & 7) * 8;
            *(s16x8*)&sm.s.A[0][r * PITCH + v] = *(const s16x8*)&Ahi[(size_t)(m0 + r) * 128 + kc + v];
            *(s16x8*)&sm.s.A[1][r * PITCH + v] = *(const s16x8*)&Alo[(size_t)(m0 + r) * 128 + kc + v];
        }
#pragma unroll
        for (int t = 0; t < 4; ++t) {                 // B: wT rows d
            int i = tid + t * 256; int r = i >> 3, v = (i & 7) * 8;
            *(s16x8*)&sm.s.B[0][r * PITCH + v] = *(const s16x8*)&Bhi[r * 128 + kc + v];
            *(s16x8*)&sm.s.B[1][r * PITCH + v] = *(const s16x8*)&Blo[r * 128 + kc + v];
        }
        __syncthreads();
#pragma unroll
        for (int ks = 0; ks < 2; ++ks) {
            const int ko = ks * 32 + lk8;
            s16x8 ahi[4], alo[4], bhi[4], blo[4];
#pragma unroll
            for (int q = 0; q < 4; ++q) {
                ahi[q] = *(const s16x8*)&sm.s.A[0][(wr + q * 16 + lm) * PITCH + ko];
                alo[q] = *(const s16x8*)&sm.s.A[1][(wr + q * 16 + lm) * PITCH + ko];
                bhi[q] = *(const s16x8*)&sm.s.B[0][(wc + q * 16 + lm) * PITCH + ko];
                blo[q] = *(const s16x8*)&sm.s.B[1][(wc + q * 16 + lm) * PITCH + ko];
            }
#pragma unroll
            for (int rt = 0; rt < 4; ++rt)
#pragma unroll
                for (int ct = 0; ct < 4; ++ct) {
                    f32x4 a = acc[rt][ct];
                    a = __builtin_amdgcn_mfma_f32_16x16x32_bf16(ahi[rt], bhi[ct], a, 0, 0, 0);
                    a = __builtin_amdgcn_mfma_f32_16x16x32_bf16(ahi[rt], blo[ct], a, 0, 0, 0);
                    a = __builtin_amdgcn_mfma_f32_16x16x32_bf16(alo[rt], bhi[ct], a, 0, 0, 0);
                    acc[rt][ct] = a;
                }
        }
        __syncthreads();
    }
    // bounce: C rows = j (within tile), cols = d
#pragma unroll
    for (int rt = 0; rt < 4; ++rt)
#pragma unroll
        for (int ct = 0; ct < 4; ++ct)
#pragma unroll
            for (int r = 0; r < 4; ++r)
                sm.bounce[(wr + rt * 16 + (lane >> 4) * 4 + r) * 129 + wc + ct * 16 + lm] = acc[rt][ct][r];
    __syncthreads();
    const int b = m0 >> 10, j0 = m0 & 1023;
    for (int t = 0; t < 32; ++t) {                    // transposed, coalesced packed stores
        int i = tid + t * 256; int d = i >> 6, j2 = (i & 63) * 2;
        float x0 = sm.bounce[j2 * 129 + d], x1 = sm.bounce[(j2 + 1) * 129 + d];
        U16 h0, l0, h1, l1; splitbf(x0, h0, l0); splitbf(x1, h1, l1);
        size_t o = (((size_t)(b * 128 + d)) << 10) + j0 + j2;
        *(U32*)&Ohi[o] = (U32)h0 | ((U32)h1 << 16);
        *(U32*)&Olo[o] = (U32)l0 | ((U32)l1 << 16);
    }
}

// ---------------- K2: m = adjT @ hw  per batch (2-product; adj exact) ----------------
__global__ __launch_bounds__(256, 2) void k_adj(
    const float* __restrict__ adj,                                // [NB][NN][NN]
    const U16* __restrict__ hwThi, const U16* __restrict__ hwTlo, // [NB][128][1024]
    U16* __restrict__ mhi, U16* __restrict__ mlo)                 // [MTOT][128]
{
    __shared__ Smem2 sm;
    const int tid = threadIdx.x;
    const int lane = tid & 63, wv = tid >> 6;
    const int wr = (wv & 1) * 64, wc = (wv >> 1) * 64;
    const int lm = lane & 15, lk8 = (lane >> 4) * 8;
    const int bt = blockIdx.x >> 3;
    const int n0 = (blockIdx.x & 7) * 128;

    f32x4 acc[4][4] = {};

    for (int kc = 0; kc < NN; kc += KT) {
        // A: adj[bt][kc+j][n0+c] -> LDS [n][j] (transpose + fp32->bf16, values exact)
#pragma unroll
        for (int t = 0; t < 8; ++t) {
            int i = tid + t * 256;                    // 0..2047 float4 slots
            int j = i >> 5, c4 = (i & 31) * 4;
            f32x4 v = *(const f32x4*)&adj[((size_t)bt << 20) + ((size_t)(kc + j) << 10) + n0 + c4];
#pragma unroll
            for (int u = 0; u < 4; ++u)
                sm.s.A[(c4 + u) * PITCH + j] = f2bf(v[u]);
        }
        // B: hwT[bt][d][kc..] direct vec copy
#pragma unroll
        for (int t = 0; t < 4; ++t) {
            int i = tid + t * 256; int d = i >> 3, v = (i & 7) * 8;
            size_t o = (((size_t)(bt * 128 + d)) << 10) + kc + v;
            *(s16x8*)&sm.s.B[0][d * PITCH + v] = *(const s16x8*)&hwThi[o];
            *(s16x8*)&sm.s.B[1][d * PITCH + v] = *(const s16x8*)&hwTlo[o];
        }
        __syncthreads();
#pragma unroll
        for (int ks = 0; ks < 2; ++ks) {
            const int ko = ks * 32 + lk8;
            s16x8 a[4], bhi[4], blo[4];
#pragma unroll
            for (int q = 0; q < 4; ++q) {
                a[q]   = *(const s16x8*)&sm.s.A[(wr + q * 16 + lm) * PITCH + ko];
                bhi[q] = *(const s16x8*)&sm.s.B[0][(wc + q * 16 + lm) * PITCH + ko];
                blo[q] = *(const s16x8*)&sm.s.B[1][(wc + q * 16 + lm) * PITCH + ko];
            }
#pragma unroll
            for (int rt = 0; rt < 4; ++rt)
#pragma unroll
                for (int ct = 0; ct < 4; ++ct) {
                    f32x4 c = acc[rt][ct];
                    c = __builtin_amdgcn_mfma_f32_16x16x32_bf16(a[rt], bhi[ct], c, 0, 0, 0);
                    c = __builtin_amdgcn_mfma_f32_16x16x32_bf16(a[rt], blo[ct], c, 0, 0, 0);
                    acc[rt][ct] = c;
                }
        }
        __syncthreads();
    }
#pragma unroll
    for (int rt = 0; rt < 4; ++rt)
#pragma unroll
        for (int ct = 0; ct < 4; ++ct)
#pragma unroll
            for (int r = 0; r < 4; ++r)
                sm.bounce[(wr + rt * 16 + (lane >> 4) * 4 + r) * 129 + wc + ct * 16 + lm] = acc[rt][ct][r];
    __syncthreads();
    for (int t = 0; t < 32; ++t) {
        int i = tid + t * 256; int n = i >> 6, d2 = (i & 63) * 2;
        float x0 = sm.bounce[n * 129 + d2], x1 = sm.bounce[n * 129 + d2 + 1];
        U16 h0, l0, h1, l1; splitbf(x0, h0, l0); splitbf(x1, h1, l1);
        size_t o = ((size_t)(bt * NN + n0 + n)) * 128 + d2;
        *(U32*)&mhi[o] = (U32)h0 | ((U32)h1 << 16);
        *(U32*)&mlo[o] = (U32)l0 | ((U32)l1 << 16);
    }
}

// ---------------- K3: gx = m @ w_ih^T / gh = h @ w_hh^T (blockIdx.z selects) ----------------
__global__ __launch_bounds__(256, 2) void k_gate(
    const U16* __restrict__ mhi, const U16* __restrict__ mlo,
    const U16* __restrict__ hhi, const U16* __restrict__ hlo,
    const U16* __restrict__ wihhi, const U16* __restrict__ wihlo,  // [384][128] layer slices
    const U16* __restrict__ whhhi, const U16* __restrict__ whhlo,
    float* __restrict__ gx, float* __restrict__ gh)                // [MTOT][384]
{
    __shared__ Smem3 sm;
    const int which = blockIdx.z;
    const U16* __restrict__ Ahi = which ? hhi : mhi;
    const U16* __restrict__ Alo = which ? hlo : mlo;
    const U16* __restrict__ Bhi = which ? whhhi : wihhi;
    const U16* __restrict__ Blo = which ? whhlo : wihlo;
    float* __restrict__ out = which ? gh : gx;

    const int tid = threadIdx.x;
    const int lane = tid & 63, wv = tid >> 6;
    const int wr = (wv & 1) * 64, wc = (wv >> 1) * 64;
    const int lm = lane & 15, lk8 = (lane >> 4) * 8;
    const int m0 = blockIdx.x * 128;
    const int g0 = blockIdx.y * 128;

    f32x4 acc[4][4] = {};

    for (int kc = 0; kc < 128; kc += KT) {
#pragma unroll
        for (int t = 0; t < 4; ++t) {
            int i = tid + t * 256; int r = i >> 3, v = (i & 7) * 8;
            *(s16x8*)&sm.s.A[0][r * PITCH + v] = *(const s16x8*)&Ahi[(size_t)(m0 + r) * 128 + kc + v];
            *(s16x8*)&sm.s.A[1][r * PITCH + v] = *(const s16x8*)&Alo[(size_t)(m0 + r) * 128 + kc + v];
        }
#pragma unroll
        for (int t = 0; t < 4; ++t) {
            int i = tid + t * 256; int r = i >> 3, v = (i & 7) * 8;
            *(s16x8*)&sm.s.B[0][r * PITCH + v] = *(const s16x8*)&Bhi[(size_t)(g0 + r) * 128 + kc + v];
            *(s16x8*)&sm.s.B[1][r * PITCH + v] = *(const s16x8*)&Blo[(size_t)(g0 + r) * 128 + kc + v];
        }
        __syncthreads();
#pragma unroll
        for (int ks = 0; ks < 2; ++ks) {
            const int ko = ks * 32 + lk8;
            s16x8 ahi[4], alo[4], bhi[4], blo[4];
#pragma unroll
            for (int q = 0; q < 4; ++q) {
                ahi[q] = *(const s16x8*)&sm.s.A[0][(wr + q * 16 + lm) * PITCH + ko];
                alo[q] = *(const s16x8*)&sm.s.A[1][(wr + q * 16 + lm) * PITCH + ko];
                bhi[q] = *(const s16x8*)&sm.s.B[0][(wc + q * 16 + lm) * PITCH + ko];
                blo[q] = *(const s16x8*)&sm.s.B[1][(wc + q * 16 + lm) * PITCH + ko];
            }
#pragma unroll
            for (int rt = 0; rt < 4; ++rt)
#pragma unroll
                for (int ct = 0; ct < 4; ++ct) {
                    f32x4 a = acc[rt][ct];
                    a = __builtin_amdgcn_mfma_f32_16x16x32_bf16(ahi[rt], bhi[ct], a, 0, 0, 0);
                    a = __builtin_amdgcn_mfma_f32_16x16x32_bf16(ahi[rt], blo[ct], a, 0, 0, 0);
                    a = __builtin_amdgcn_mfma_f32_16x16x32_bf16(alo[rt], bhi[ct], a, 0, 0, 0);
                    acc[rt][ct] = a;
                }
        }
        __syncthreads();
    }
#pragma unroll
    for (int rt = 0; rt < 4; ++rt)
#pragma unroll
        for (int ct = 0; ct < 4; ++ct)
#pragma unroll
            for (int r = 0; r < 4; ++r)
                sm.bounce[(wr + rt * 16 + (lane >> 4) * 4 + r) * 129 + wc + ct * 16 + lm] = acc[rt][ct][r];
    __syncthreads();
    for (int t = 0; t < 16; ++t) {
        int i = tid + t * 256; int m = i >> 5, g4 = (i & 31) * 4;
        f32x4 v;
        v[0] = sm.bounce[m * 129 + g4 + 0];
        v[1] = sm.bounce[m * 129 + g4 + 1];
        v[2] = sm.bounce[m * 129 + g4 + 2];
        v[3] = sm.bounce[m * 129 + g4 + 3];
        *(f32x4*)&out[(size_t)(m0 + m) * 384 + g0 + g4] = v;
    }
}

// ---------------- GRU elementwise ----------------
__global__ __launch_bounds__(256) void k_gru(
    const float* __restrict__ gx, const float* __restrict__ gh,
    const float* __restrict__ bih, const float* __restrict__ bhh,  // layer slices [384]
    const float* __restrict__ hin, const float* __restrict__ mask,
    float* __restrict__ hout, U16* __restrict__ hhi, U16* __restrict__ hlo,
    float* __restrict__ out, int last)
{
    int idx = blockIdx.x * 256 + threadIdx.x;      // MTOT*NC
    int row = idx >> 7, c = idx & 127;
    size_t ro = (size_t)row * 384;
    float xr = gx[ro + c]       + bih[c];
    float xz = gx[ro + 128 + c] + bih[128 + c];
    float xn = gx[ro + 256 + c] + bih[256 + c];
    float hr = gh[ro + c]       + bhh[c];
    float hz = gh[ro + 128 + c] + bhh[128 + c];
    float hn = gh[ro + 256 + c] + bhh[256 + c];
    float hv = hin[idx];
    float r = 1.f / (1.f + expf(-(xr + hr)));
    float z = 1.f / (1.f + expf(-(xz + hz)));
    float n = tanhf(xn + r * hn);
    float hnew = (1.f - z) * n + z * hv;
    if (last) {
        out[idx] = hnew * mask[row];
    } else {
        hout[idx] = hnew;
        U16 hi, lo; splitbf(hnew, hi, lo);
        hhi[idx] = hi; hlo[idx] = lo;
    }
}

// ---------------- prep: split/transpose weights ----------------
__global__ __launch_bounds__(256) void k_prep(
    const float* __restrict__ w, const float* __restrict__ wih, const float* __restrict__ whh,
    U16* __restrict__ wThi, U16* __restrict__ wTlo,
    U16* __restrict__ wihhi, U16* __restrict__ wihlo,
    U16* __restrict__ whhhi, U16* __restrict__ whhlo)
{
    int i = blockIdx.x * 256 + threadIdx.x;        // 458752
    if (i < 65536) {                               // weight [L][C][C] -> wT [L][d][c]
        int l = i >> 14, rem = i & 16383, c = rem >> 7, d = rem & 127;
        U16 hi, lo; splitbf(w[i], hi, lo);
        int o = (l << 14) + (d << 7) + c;
        wThi[o] = hi; wTlo[o] = lo;
    } else if (i < 262144) {                       // w_ih direct [L][384][128]
        int j = i - 65536;
        U16 hi, lo; splitbf(wih[j], hi, lo);
        wihhi[j] = hi; wihlo[j] = lo;
    } else {                                       // w_hh direct
        int j = i - 262144;
        U16 hi, lo; splitbf(whh[j], hi, lo);
        whhhi[j] = hi; whhlo[j] = lo;
    }
}

__global__ __launch_bounds__(256) void k_init(const float* __restrict__ x,
                                              U16* __restrict__ hhi, U16* __restrict__ hlo)
{
    int i = blockIdx.x * 256 + threadIdx.x;
    U16 hi, lo; splitbf(x[i], hi, lo);
    hhi[i] = hi; hlo[i] = lo;
}

// ---------------- launch ----------------
extern "C" void kernel_launch(void* const* d_in, const int* in_sizes, int n_in,
                              void* d_out, int out_size, void* d_ws, size_t ws_size,
                              hipStream_t stream) {
    (void)in_sizes; (void)n_in; (void)out_size; (void)ws_size;
    const float* x    = (const float*)d_in[0];
    const float* adj  = (const float*)d_in[1];
    const float* mask = (const float*)d_in[2];
    const float* wgt  = (const float*)d_in[3];
    const float* wih  = (const float*)d_in[4];
    const float* whh  = (const float*)d_in[5];
    const float* bih  = (const float*)d_in[6];
    const float* bhh  = (const float*)d_in[7];
    float* out = (float*)d_out;

    char* p = (char*)d_ws;
    float* h_f32 = (float*)p;              p += (size_t)MTOT * NC * 4;    // 16.8 MB
    U16* h_hi    = (U16*)p;                p += (size_t)MTOT * NC * 2;
    U16* h_lo    = (U16*)p;                p += (size_t)MTOT * NC * 2;
    U16* hwT_hi  = (U16*)p;                p += (size_t)NB * NC * NN * 2;
    U16* hwT_lo  = (U16*)p;                p += (size_t)NB * NC * NN * 2;
    U16* m_hi    = (U16*)p;                p += (size_t)MTOT * NC * 2;
    U16* m_lo    = (U16*)p;                p += (size_t)MTOT * NC * 2;
    float* gx    = (float*)p;              p += (size_t)MTOT * 384 * 4;   // 50.3 MB
    float* gh    = (float*)p;              p += (size_t)MTOT * 384 * 4;
    U16* wT_hi   = (U16*)p;                p += (size_t)NL * NC * NC * 2;
    U16* wT_lo   = (U16*)p;                p += (size_t)NL * NC * NC * 2;
    U16* wih_hi  = (U16*)p;                p += (size_t)NL * 384 * NC * 2;
    U16* wih_lo  = (U16*)p;                p += (size_t)NL * 384 * NC * 2;
    U16* whh_hi  = (U16*)p;                p += (size_t)NL * 384 * NC * 2;
    U16* whh_lo  = (U16*)p;                p += (size_t)NL * 384 * NC * 2;

    k_prep<<<1792, 256, 0, stream>>>(wgt, wih, whh, wT_hi, wT_lo, wih_hi, wih_lo, whh_hi, whh_lo);
    k_init<<<16384, 256, 0, stream>>>(x, h_hi, h_lo);

    for (int l = 0; l < NL; ++l) {
        k_hw<<<256, 256, 0, stream>>>(h_hi, h_lo,
                                      wT_hi + l * 16384, wT_lo + l * 16384,
                                      hwT_hi, hwT_lo);
        k_adj<<<256, 256, 0, stream>>>(adj, hwT_hi, hwT_lo, m_hi, m_lo);
        k_gate<<<dim3(256, 3, 2), 256, 0, stream>>>(m_hi, m_lo, h_hi, h_lo,
                                                    wih_hi + l * 49152, wih_lo + l * 49152,
                                                    whh_hi + l * 49152, whh_lo + l * 49152,
                                                    gx, gh);
        k_gru<<<16384, 256, 0, stream>>>(gx, gh, bih + l * 384, bhh + l * 384,
                                         (l == 0 ? x : (const float*)h_f32), mask,
                                         h_f32, h_hi, h_lo, out, (l == NL - 1) ? 1 : 0);
    }
}

// Round 2
// 658.593 us; speedup vs baseline: 1.2134x; 1.2134x over previous
//
#include <hip/hip_runtime.h>
#include <stdint.h>

// DenseGGNN on MI355X, round 2.
//  - adj pre-transposed/converted ONCE to bf16 adjT[b][n][j] (exact: adj in {0,1})
//    -> k_adj staging is pure vectorized copy (kills 16-way ds_write_b16 conflicts).
//  - k_gate + k_gru fused: r/z accumulated over concat-K=256 ([m|h] @ [wih|whh]^T),
//    xn/hn separate, GRU in-register, h for z*h read from LDS stage (hi+lo).
//    Eliminates 200 MB/layer gx/gh round-trip.

#define NB 32
#define NN 1024
#define NC 128
#define NL 4
#define MTOT (NB * NN)   // 32768

#define KT 64
#define PITCH 72         // 144B row stride: 16B aligned, bank step 4 -> <=2-way conflicts

typedef __attribute__((ext_vector_type(8))) short s16x8;
typedef __attribute__((ext_vector_type(4))) float f32x4;
typedef __attribute__((ext_vector_type(2))) unsigned int u32x2;
typedef unsigned short U16;
typedef unsigned int U32;

__device__ __forceinline__ U16 f2bf(float f) {
    union { float f; U32 u; } v; v.f = f;
    return (U16)((v.u + 0x7FFFu + ((v.u >> 16) & 1u)) >> 16);  // RNE
}
__device__ __forceinline__ float bf2f(U16 h) {
    union { U32 u; float f; } v; v.u = ((U32)h) << 16;
    return v.f;
}
__device__ __forceinline__ void splitbf(float x, U16& hi, U16& lo) {
    hi = f2bf(x);
    lo = f2bf(x - bf2f(hi));
}
__device__ __forceinline__ float sigmoidf_(float x) { return 1.f / (1.f + __expf(-x)); }

// ---------------- shared-memory tiles ----------------
struct __align__(16) Smem3 {               // k_hw: A hi/lo + B hi/lo
    union {
        struct { U16 A[2][128 * PITCH]; U16 B[2][128 * PITCH]; } s;   // 73728 B
        float bounce[128 * 129];                                      // 66048 B
    };
};
struct __align__(16) Smem2 {               // k_adj: A single + B hi/lo
    union {
        struct { U16 A[128 * PITCH]; U16 B[2][128 * PITCH]; } s;      // 55296 B
        float bounce[128 * 129];                                      // 66048 B
    };
};

// ---------------- adj transpose: adj fp32 [b][j][n] -> adjT bf16 [b][n][j] (once) ----------------
__global__ __launch_bounds__(256) void k_adjT(const float* __restrict__ adj,
                                              U16* __restrict__ adjT)
{
    __shared__ float t[64 * 65];           // pitch 65: read stride 4*65%32=4 -> 2-way max
    const int b = blockIdx.z, j0 = blockIdx.x * 64, n0 = blockIdx.y * 64;
    const int tid = threadIdx.x;
    const int rr = tid >> 4, c4 = (tid & 15) * 4;
#pragma unroll
    for (int p = 0; p < 4; ++p) {
        int j = p * 16 + rr;
        f32x4 v = *(const f32x4*)&adj[((size_t)b << 20) + ((size_t)(j0 + j) << 10) + n0 + c4];
#pragma unroll
        for (int u = 0; u < 4; ++u) t[j * 65 + c4 + u] = v[u];
    }
    __syncthreads();
#pragma unroll
    for (int p = 0; p < 4; ++p) {
        int n = p * 16 + rr;               // output row (target node)
        U16 h0 = f2bf(t[(c4 + 0) * 65 + n]);
        U16 h1 = f2bf(t[(c4 + 1) * 65 + n]);
        U16 h2 = f2bf(t[(c4 + 2) * 65 + n]);
        U16 h3 = f2bf(t[(c4 + 3) * 65 + n]);
        u32x2 pk; pk[0] = (U32)h0 | ((U32)h1 << 16); pk[1] = (U32)h2 | ((U32)h3 << 16);
        *(u32x2*)&adjT[((size_t)b << 20) + ((size_t)(n0 + n) << 10) + j0 + c4] = pk;
    }
}

// ---------------- K1: hw = h @ W (3-product), writes hwT[b][d][j] hi/lo ----------------
__global__ __launch_bounds__(256, 2) void k_hw(
    const U16* __restrict__ Ahi, const U16* __restrict__ Alo,   // h   [MTOT][128]
    const U16* __restrict__ Bhi, const U16* __restrict__ Blo,   // wT  [128][128] (layer slice)
    U16* __restrict__ Ohi, U16* __restrict__ Olo)               // hwT [NB][128][1024]
{
    __shared__ Smem3 sm;
    const int tid = threadIdx.x;
    const int lane = tid & 63, wv = tid >> 6;
    const int wr = (wv & 1) * 64, wc = (wv >> 1) * 64;
    const int lm = lane & 15, lk8 = (lane >> 4) * 8;
    const int m0 = blockIdx.x * 128;

    f32x4 acc[4][4] = {};

    for (int kc = 0; kc < 128; kc += KT) {
#pragma unroll
        for (int t = 0; t < 4; ++t) {
            int i = tid + t * 256; int r = i >> 3, v = (i & 7) * 8;
            *(s16x8*)&sm.s.A[0][r * PITCH + v] = *(const s16x8*)&Ahi[(size_t)(m0 + r) * 128 + kc + v];
            *(s16x8*)&sm.s.A[1][r * PITCH + v] = *(const s16x8*)&Alo[(size_t)(m0 + r) * 128 + kc + v];
        }
#pragma unroll
        for (int t = 0; t < 4; ++t) {
            int i = tid + t * 256; int r = i >> 3, v = (i & 7) * 8;
            *(s16x8*)&sm.s.B[0][r * PITCH + v] = *(const s16x8*)&Bhi[r * 128 + kc + v];
            *(s16x8*)&sm.s.B[1][r * PITCH + v] = *(const s16x8*)&Blo[r * 128 + kc + v];
        }
        __syncthreads();
#pragma unroll
        for (int ks = 0; ks < 2; ++ks) {
            const int ko = ks * 32 + lk8;
            s16x8 ahi[4], alo[4], bhi[4], blo[4];
#pragma unroll
            for (int q = 0; q < 4; ++q) {
                ahi[q] = *(const s16x8*)&sm.s.A[0][(wr + q * 16 + lm) * PITCH + ko];
                alo[q] = *(const s16x8*)&sm.s.A[1][(wr + q * 16 + lm) * PITCH + ko];
                bhi[q] = *(const s16x8*)&sm.s.B[0][(wc + q * 16 + lm) * PITCH + ko];
                blo[q] = *(const s16x8*)&sm.s.B[1][(wc + q * 16 + lm) * PITCH + ko];
            }
#pragma unroll
            for (int rt = 0; rt < 4; ++rt)
#pragma unroll
                for (int ct = 0; ct < 4; ++ct) {
                    f32x4 a = acc[rt][ct];
                    a = __builtin_amdgcn_mfma_f32_16x16x32_bf16(ahi[rt], bhi[ct], a, 0, 0, 0);
                    a = __builtin_amdgcn_mfma_f32_16x16x32_bf16(ahi[rt], blo[ct], a, 0, 0, 0);
                    a = __builtin_amdgcn_mfma_f32_16x16x32_bf16(alo[rt], bhi[ct], a, 0, 0, 0);
                    acc[rt][ct] = a;
                }
        }
        __syncthreads();
    }
#pragma unroll
    for (int rt = 0; rt < 4; ++rt)
#pragma unroll
        for (int ct = 0; ct < 4; ++ct)
#pragma unroll
            for (int r = 0; r < 4; ++r)
                sm.bounce[(wr + rt * 16 + (lane >> 4) * 4 + r) * 129 + wc + ct * 16 + lm] = acc[rt][ct][r];
    __syncthreads();
    const int b = m0 >> 10, j0 = m0 & 1023;
    for (int t = 0; t < 32; ++t) {
        int i = tid + t * 256; int d = i >> 6, j2 = (i & 63) * 2;
        float x0 = sm.bounce[j2 * 129 + d], x1 = sm.bounce[(j2 + 1) * 129 + d];
        U16 h0, l0, h1, l1; splitbf(x0, h0, l0); splitbf(x1, h1, l1);
        size_t o = (((size_t)(b * 128 + d)) << 10) + j0 + j2;
        *(U32*)&Ohi[o] = (U32)h0 | ((U32)h1 << 16);
        *(U32*)&Olo[o] = (U32)l0 | ((U32)l1 << 16);
    }
}

// ---------------- K2: m = adjT @ hw per batch (2-product; adj exact) ----------------
__global__ __launch_bounds__(256, 2) void k_adj(
    const U16* __restrict__ adjT,                                 // [NB][NN][NN] bf16
    const U16* __restrict__ hwThi, const U16* __restrict__ hwTlo, // [NB][128][1024]
    U16* __restrict__ mhi, U16* __restrict__ mlo)                 // [MTOT][128]
{
    __shared__ Smem2 sm;
    const int tid = threadIdx.x;
    const int lane = tid & 63, wv = tid >> 6;
    const int wr = (wv & 1) * 64, wc = (wv >> 1) * 64;
    const int lm = lane & 15, lk8 = (lane >> 4) * 8;
    const int bt = blockIdx.x >> 3;
    const int n0 = (blockIdx.x & 7) * 128;

    f32x4 acc[4][4] = {};

    for (int kc = 0; kc < NN; kc += KT) {
        // A: adjT[bt][n0+r][kc..] pure vec copy (no transpose, no conflicts)
#pragma unroll
        for (int t = 0; t < 4; ++t) {
            int i = tid + t * 256; int r = i >> 3, v = (i & 7) * 8;
            *(s16x8*)&sm.s.A[r * PITCH + v] =
                *(const s16x8*)&adjT[((size_t)bt << 20) + ((size_t)(n0 + r) << 10) + kc + v];
        }
        // B: hwT[bt][d][kc..] direct vec copy
#pragma unroll
        for (int t = 0; t < 4; ++t) {
            int i = tid + t * 256; int d = i >> 3, v = (i & 7) * 8;
            size_t o = (((size_t)(bt * 128 + d)) << 10) + kc + v;
            *(s16x8*)&sm.s.B[0][d * PITCH + v] = *(const s16x8*)&hwThi[o];
            *(s16x8*)&sm.s.B[1][d * PITCH + v] = *(const s16x8*)&hwTlo[o];
        }
        __syncthreads();
#pragma unroll
        for (int ks = 0; ks < 2; ++ks) {
            const int ko = ks * 32 + lk8;
            s16x8 a[4], bhi[4], blo[4];
#pragma unroll
            for (int q = 0; q < 4; ++q) {
                a[q]   = *(const s16x8*)&sm.s.A[(wr + q * 16 + lm) * PITCH + ko];
                bhi[q] = *(const s16x8*)&sm.s.B[0][(wc + q * 16 + lm) * PITCH + ko];
                blo[q] = *(const s16x8*)&sm.s.B[1][(wc + q * 16 + lm) * PITCH + ko];
            }
#pragma unroll
            for (int rt = 0; rt < 4; ++rt)
#pragma unroll
                for (int ct = 0; ct < 4; ++ct) {
                    f32x4 c = acc[rt][ct];
                    c = __builtin_amdgcn_mfma_f32_16x16x32_bf16(a[rt], bhi[ct], c, 0, 0, 0);
                    c = __builtin_amdgcn_mfma_f32_16x16x32_bf16(a[rt], blo[ct], c, 0, 0, 0);
                    acc[rt][ct] = c;
                }
        }
        __syncthreads();
    }
#pragma unroll
    for (int rt = 0; rt < 4; ++rt)
#pragma unroll
        for (int ct = 0; ct < 4; ++ct)
#pragma unroll
            for (int r = 0; r < 4; ++r)
                sm.bounce[(wr + rt * 16 + (lane >> 4) * 4 + r) * 129 + wc + ct * 16 + lm] = acc[rt][ct][r];
    __syncthreads();
    for (int t = 0; t < 32; ++t) {
        int i = tid + t * 256; int n = i >> 6, d2 = (i & 63) * 2;
        float x0 = sm.bounce[n * 129 + d2], x1 = sm.bounce[n * 129 + d2 + 1];
        U16 h0, l0, h1, l1; splitbf(x0, h0, l0); splitbf(x1, h1, l1);
        size_t o = ((size_t)(bt * NN + n0 + n)) * 128 + d2;
        *(U32*)&mhi[o] = (U32)h0 | ((U32)h1 << 16);
        *(U32*)&mlo[o] = (U32)l0 | ((U32)l1 << 16);
    }
}

// ---------------- K3 fused: gates + GRU. Per block: 128 rows, all 384 gate cols. ----------------
// accR/accZ accumulate over concat-K=256 ([m|h] @ [wih_g|whh_g]^T); accXN (A=m), accHN (A=h).
// B-fragments loaded straight from global (L2-hot weights). GRU applied in-register;
// h for the z*h term reconstructed from the LDS h-stage (hi+lo).
#define FP 72
__global__ __launch_bounds__(256, 1) void k_fused(
    const U16* __restrict__ mhi, const U16* __restrict__ mlo,    // [MTOT][128]
    const U16* __restrict__ hhi, const U16* __restrict__ hlo,    // [MTOT][128]
    const U16* __restrict__ wihhi, const U16* __restrict__ wihlo,// [384][128] layer slice
    const U16* __restrict__ whhhi, const U16* __restrict__ whhlo,
    const float* __restrict__ bih, const float* __restrict__ bhh,// [384] layer slice
    const float* __restrict__ mask,                              // [MTOT]
    U16* __restrict__ houthi, U16* __restrict__ houtlo,
    float* __restrict__ out, int last)
{
    __shared__ U16 A[4][2][128 * FP];      // chunk 0,1: m k0/k64; chunk 2,3: h. 147456 B
    const int tid = threadIdx.x;
    const int lane = tid & 63, wv = tid >> 6;
    const int wr = (wv & 1) * 64, wc = (wv >> 1) * 64;
    const int lm = lane & 15, lk8 = (lane >> 4) * 8, quad = lane >> 4;
    const int m0 = blockIdx.x * 128;

    // stage all four K-chunks (m hi/lo, h hi/lo) up front: one barrier total
    for (int ch = 0; ch < 4; ++ch) {
        const U16* shi = (ch < 2) ? mhi : hhi;
        const U16* slo = (ch < 2) ? mlo : hlo;
        const int kb = (ch & 1) * 64;
#pragma unroll
        for (int t = 0; t < 4; ++t) {
            int i = tid + t * 256; int r = i >> 3, v = (i & 7) * 8;
            *(s16x8*)&A[ch][0][r * FP + v] = *(const s16x8*)&shi[(size_t)(m0 + r) * 128 + kb + v];
            *(s16x8*)&A[ch][1][r * FP + v] = *(const s16x8*)&slo[(size_t)(m0 + r) * 128 + kb + v];
        }
    }
    __syncthreads();

    // init accumulators with biases (per output col)
    f32x4 aR[4][4], aZ[4][4], aXN[4][4], aHN[4][4];
#pragma unroll
    for (int ct = 0; ct < 4; ++ct) {
        const int col = wc + ct * 16 + lm;
        const float bR  = bih[col]       + bhh[col];
        const float bZ  = bih[128 + col] + bhh[128 + col];
        const float bXN = bih[256 + col];
        const float bHN = bhh[256 + col];
#pragma unroll
        for (int rt = 0; rt < 4; ++rt) {
            aR[rt][ct]  = f32x4{bR, bR, bR, bR};
            aZ[rt][ct]  = f32x4{bZ, bZ, bZ, bZ};
            aXN[rt][ct] = f32x4{bXN, bXN, bXN, bXN};
            aHN[rt][ct] = f32x4{bHN, bHN, bHN, bHN};
        }
    }

    for (int ch = 0; ch < 4; ++ch) {
        const U16* __restrict__ Whi = (ch < 2) ? wihhi : whhhi;
        const U16* __restrict__ Wlo = (ch < 2) ? wihlo : whhlo;
        const int kb = (ch & 1) * 64;
#pragma unroll
        for (int ks = 0; ks < 2; ++ks) {
            const int ko = ks * 32 + lk8;
            const int kg = kb + ko;                     // k within [0,128) for weights
            s16x8 ahi[4], alo[4];
#pragma unroll
            for (int q = 0; q < 4; ++q) {
                ahi[q] = *(s16x8*)&A[ch][0][(wr + q * 16 + lm) * FP + ko];
                alo[q] = *(s16x8*)&A[ch][1][(wr + q * 16 + lm) * FP + ko];
            }
            // gate r (rows 0..127) and z (rows 128..255): shared accumulation
#pragma unroll
            for (int ct = 0; ct < 4; ++ct) {
                const int colr = wc + ct * 16 + lm;
                s16x8 bhiR = *(const s16x8*)&Whi[(size_t)colr * 128 + kg];
                s16x8 bloR = *(const s16x8*)&Wlo[(size_t)colr * 128 + kg];
                s16x8 bhiZ = *(const s16x8*)&Whi[(size_t)(128 + colr) * 128 + kg];
                s16x8 bloZ = *(const s16x8*)&Wlo[(size_t)(128 + colr) * 128 + kg];
                s16x8 bhiN = *(const s16x8*)&Whi[(size_t)(256 + colr) * 128 + kg];
                s16x8 bloN = *(const s16x8*)&Wlo[(size_t)(256 + colr) * 128 + kg];
#pragma unroll
                for (int rt = 0; rt < 4; ++rt) {
                    f32x4 r = aR[rt][ct];
                    r = __builtin_amdgcn_mfma_f32_16x16x32_bf16(ahi[rt], bhiR, r, 0, 0, 0);
                    r = __builtin_amdgcn_mfma_f32_16x16x32_bf16(ahi[rt], bloR, r, 0, 0, 0);
                    r = __builtin_amdgcn_mfma_f32_16x16x32_bf16(alo[rt], bhiR, r, 0, 0, 0);
                    aR[rt][ct] = r;
                    f32x4 z = aZ[rt][ct];
                    z = __builtin_amdgcn_mfma_f32_16x16x32_bf16(ahi[rt], bhiZ, z, 0, 0, 0);
                    z = __builtin_amdgcn_mfma_f32_16x16x32_bf16(ahi[rt], bloZ, z, 0, 0, 0);
                    z = __builtin_amdgcn_mfma_f32_16x16x32_bf16(alo[rt], bhiZ, z, 0, 0, 0);
                    aZ[rt][ct] = z;
                }
                if (ch < 2) {
#pragma unroll
                    for (int rt = 0; rt < 4; ++rt) {
                        f32x4 n = aXN[rt][ct];
                        n = __builtin_amdgcn_mfma_f32_16x16x32_bf16(ahi[rt], bhiN, n, 0, 0, 0);
                        n = __builtin_amdgcn_mfma_f32_16x16x32_bf16(ahi[rt], bloN, n, 0, 0, 0);
                        n = __builtin_amdgcn_mfma_f32_16x16x32_bf16(alo[rt], bhiN, n, 0, 0, 0);
                        aXN[rt][ct] = n;
                    }
                } else {
#pragma unroll
                    for (int rt = 0; rt < 4; ++rt) {
                        f32x4 n = aHN[rt][ct];
                        n = __builtin_amdgcn_mfma_f32_16x16x32_bf16(ahi[rt], bhiN, n, 0, 0, 0);
                        n = __builtin_amdgcn_mfma_f32_16x16x32_bf16(ahi[rt], bloN, n, 0, 0, 0);
                        n = __builtin_amdgcn_mfma_f32_16x16x32_bf16(alo[rt], bhiN, n, 0, 0, 0);
                        aHN[rt][ct] = n;
                    }
                }
            }
        }
    }

    // GRU epilogue in-register; h from LDS h-stage (hi+lo)
#pragma unroll
    for (int rt = 0; rt < 4; ++rt) {
#pragma unroll
        for (int ct = 0; ct < 4; ++ct) {
            const int col = wc + ct * 16 + lm;
            const int hch = 2 + (col >> 6), hko = col & 63;
#pragma unroll
            for (int rr = 0; rr < 4; ++rr) {
                const int rloc = wr + rt * 16 + quad * 4 + rr;
                const int row = m0 + rloc;
                float r = sigmoidf_(aR[rt][ct][rr]);
                float z = sigmoidf_(aZ[rt][ct][rr]);
                float n = tanhf(aXN[rt][ct][rr] + r * aHN[rt][ct][rr]);
                float hv = bf2f(A[hch][0][rloc * FP + hko]) + bf2f(A[hch][1][rloc * FP + hko]);
                float hnew = (1.f - z) * n + z * hv;
                if (last) {
                    out[(size_t)row * 128 + col] = hnew * mask[row];
                } else {
                    U16 hi2, lo2; splitbf(hnew, hi2, lo2);
                    houthi[(size_t)row * 128 + col] = hi2;
                    houtlo[(size_t)row * 128 + col] = lo2;
                }
            }
        }
    }
}

// ---------------- prep: split/transpose weights ----------------
__global__ __launch_bounds__(256) void k_prep(
    const float* __restrict__ w, const float* __restrict__ wih, const float* __restrict__ whh,
    U16* __restrict__ wThi, U16* __restrict__ wTlo,
    U16* __restrict__ wihhi, U16* __restrict__ wihlo,
    U16* __restrict__ whhhi, U16* __restrict__ whhlo)
{
    int i = blockIdx.x * 256 + threadIdx.x;        // 458752
    if (i < 65536) {                               // weight [L][C][C] -> wT [L][d][c]
        int l = i >> 14, rem = i & 16383, c = rem >> 7, d = rem & 127;
        U16 hi, lo; splitbf(w[i], hi, lo);
        int o = (l << 14) + (d << 7) + c;
        wThi[o] = hi; wTlo[o] = lo;
    } else if (i < 262144) {                       // w_ih direct [L][384][128]
        int j = i - 65536;
        U16 hi, lo; splitbf(wih[j], hi, lo);
        wihhi[j] = hi; wihlo[j] = lo;
    } else {                                       // w_hh direct
        int j = i - 262144;
        U16 hi, lo; splitbf(whh[j], hi, lo);
        whhhi[j] = hi; whhlo[j] = lo;
    }
}

__global__ __launch_bounds__(256) void k_init(const float* __restrict__ x,
                                              U16* __restrict__ hhi, U16* __restrict__ hlo)
{
    int i = blockIdx.x * 256 + threadIdx.x;
    U16 hi, lo; splitbf(x[i], hi, lo);
    hhi[i] = hi; hlo[i] = lo;
}

// ---------------- launch ----------------
extern "C" void kernel_launch(void* const* d_in, const int* in_sizes, int n_in,
                              void* d_out, int out_size, void* d_ws, size_t ws_size,
                              hipStream_t stream) {
    (void)in_sizes; (void)n_in; (void)out_size; (void)ws_size;
    const float* x    = (const float*)d_in[0];
    const float* adj  = (const float*)d_in[1];
    const float* mask = (const float*)d_in[2];
    const float* wgt  = (const float*)d_in[3];
    const float* wih  = (const float*)d_in[4];
    const float* whh  = (const float*)d_in[5];
    const float* bih  = (const float*)d_in[6];
    const float* bhh  = (const float*)d_in[7];
    float* out = (float*)d_out;

    char* p = (char*)d_ws;
    U16* adjT    = (U16*)p;                p += (size_t)NB * NN * NN * 2;   // 67.1 MB
    U16* h_hi    = (U16*)p;                p += (size_t)MTOT * NC * 2;
    U16* h_lo    = (U16*)p;                p += (size_t)MTOT * NC * 2;
    U16* hwT_hi  = (U16*)p;                p += (size_t)NB * NC * NN * 2;
    U16* hwT_lo  = (U16*)p;                p += (size_t)NB * NC * NN * 2;
    U16* m_hi    = (U16*)p;                p += (size_t)MTOT * NC * 2;
    U16* m_lo    = (U16*)p;                p += (size_t)MTOT * NC * 2;
    U16* wT_hi   = (U16*)p;                p += (size_t)NL * NC * NC * 2;
    U16* wT_lo   = (U16*)p;                p += (size_t)NL * NC * NC * 2;
    U16* wih_hi  = (U16*)p;                p += (size_t)NL * 384 * NC * 2;
    U16* wih_lo  = (U16*)p;                p += (size_t)NL * 384 * NC * 2;
    U16* whh_hi  = (U16*)p;                p += (size_t)NL * 384 * NC * 2;
    U16* whh_lo  = (U16*)p;                p += (size_t)NL * 384 * NC * 2;

    k_prep<<<1792, 256, 0, stream>>>(wgt, wih, whh, wT_hi, wT_lo, wih_hi, wih_lo, whh_hi, whh_lo);
    k_init<<<16384, 256, 0, stream>>>(x, h_hi, h_lo);
    k_adjT<<<dim3(16, 16, NB), 256, 0, stream>>>(adj, adjT);

    for (int l = 0; l < NL; ++l) {
        k_hw<<<256, 256, 0, stream>>>(h_hi, h_lo,
                                      wT_hi + l * 16384, wT_lo + l * 16384,
                                      hwT_hi, hwT_lo);
        k_adj<<<256, 256, 0, stream>>>(adjT, hwT_hi, hwT_lo, m_hi, m_lo);
        k_fused<<<256, 256, 0, stream>>>(m_hi, m_lo, h_hi, h_lo,
                                         wih_hi + l * 49152, wih_lo + l * 49152,
                                         whh_hi + l * 49152, whh_lo + l * 49152,
                                         bih + l * 384, bhh + l * 384, mask,
                                         h_hi, h_lo, out, (l == NL - 1) ? 1 : 0);
    }
}

// Round 3
// 656.700 us; speedup vs baseline: 1.2169x; 1.0029x over previous
//
#include <hip/hip_runtime.h>
#include <stdint.h>

// DenseGGNN on MI355X, round 3.
//  - k_adj rebuilt m97-style: global_load_lds width-16 staging, 128n x 64d tile,
//    512 blocks, 32 KB LDS -> 2 resident blocks/CU (vs 1), unpadded [row][64] LDS.
//  - k_fused: zero LDS, A-fragments loaded per-lane direct from global (L2-hot),
//    no barriers; h for z*h re-read from global in epilogue.

#define NB 32
#define NN 1024
#define NC 128
#define NL 4
#define MTOT (NB * NN)   // 32768

#define KT 64
#define PITCH 72         // k_hw LDS pitch: 16B aligned, bank step 4 -> <=2-way conflicts

typedef __attribute__((ext_vector_type(8))) short s16x8;
typedef __attribute__((ext_vector_type(4))) float f32x4;
typedef __attribute__((ext_vector_type(2))) unsigned int u32x2;
typedef unsigned short U16;
typedef unsigned int U32;

__device__ __forceinline__ U16 f2bf(float f) {
    union { float f; U32 u; } v; v.f = f;
    return (U16)((v.u + 0x7FFFu + ((v.u >> 16) & 1u)) >> 16);  // RNE
}
__device__ __forceinline__ float bf2f(U16 h) {
    union { U32 u; float f; } v; v.u = ((U32)h) << 16;
    return v.f;
}
__device__ __forceinline__ void splitbf(float x, U16& hi, U16& lo) {
    hi = f2bf(x);
    lo = f2bf(x - bf2f(hi));
}
__device__ __forceinline__ float sigmoidf_(float x) { return 1.f / (1.f + __expf(-x)); }

// async global->LDS, 16 B per lane; LDS dest must be wave-uniform base + lane*16
__device__ __forceinline__ void glds16(const void* g, void* l) {
    __builtin_amdgcn_global_load_lds(
        (const __attribute__((address_space(1))) void*)g,
        (__attribute__((address_space(3))) void*)l, 16, 0, 0);
}

// ---------------- k_hw shared tile ----------------
struct __align__(16) Smem3 {               // A hi/lo + B hi/lo
    union {
        struct { U16 A[2][128 * PITCH]; U16 B[2][128 * PITCH]; } s;   // 73728 B
        float bounce[128 * 129];                                      // 66048 B
    };
};

// ---------------- adj transpose: adj fp32 [b][j][n] -> adjT bf16 [b][n][j] (once) ----------------
__global__ __launch_bounds__(256) void k_adjT(const float* __restrict__ adj,
                                              U16* __restrict__ adjT)
{
    __shared__ float t[64 * 65];
    const int b = blockIdx.z, j0 = blockIdx.x * 64, n0 = blockIdx.y * 64;
    const int tid = threadIdx.x;
    const int rr = tid >> 4, c4 = (tid & 15) * 4;
#pragma unroll
    for (int p = 0; p < 4; ++p) {
        int j = p * 16 + rr;
        f32x4 v = *(const f32x4*)&adj[((size_t)b << 20) + ((size_t)(j0 + j) << 10) + n0 + c4];
#pragma unroll
        for (int u = 0; u < 4; ++u) t[j * 65 + c4 + u] = v[u];
    }
    __syncthreads();
#pragma unroll
    for (int p = 0; p < 4; ++p) {
        int n = p * 16 + rr;
        U16 h0 = f2bf(t[(c4 + 0) * 65 + n]);
        U16 h1 = f2bf(t[(c4 + 1) * 65 + n]);
        U16 h2 = f2bf(t[(c4 + 2) * 65 + n]);
        U16 h3 = f2bf(t[(c4 + 3) * 65 + n]);
        u32x2 pk; pk[0] = (U32)h0 | ((U32)h1 << 16); pk[1] = (U32)h2 | ((U32)h3 << 16);
        *(u32x2*)&adjT[((size_t)b << 20) + ((size_t)(n0 + n) << 10) + j0 + c4] = pk;
    }
}

// ---------------- K1: hw = h @ W (3-product), writes hwT[b][d][j] hi/lo ----------------
__global__ __launch_bounds__(256, 2) void k_hw(
    const U16* __restrict__ Ahi, const U16* __restrict__ Alo,   // h   [MTOT][128]
    const U16* __restrict__ Bhi, const U16* __restrict__ Blo,   // wT  [128][128] (layer slice)
    U16* __restrict__ Ohi, U16* __restrict__ Olo)               // hwT [NB][128][1024]
{
    __shared__ Smem3 sm;
    const int tid = threadIdx.x;
    const int lane = tid & 63, wv = tid >> 6;
    const int wr = (wv & 1) * 64, wc = (wv >> 1) * 64;
    const int lm = lane & 15, lk8 = (lane >> 4) * 8;
    const int m0 = blockIdx.x * 128;

    f32x4 acc[4][4] = {};

    for (int kc = 0; kc < 128; kc += KT) {
#pragma unroll
        for (int t = 0; t < 4; ++t) {
            int i = tid + t * 256; int r = i >> 3, v = (i & 7) * 8;
            *(s16x8*)&sm.s.A[0][r * PITCH + v] = *(const s16x8*)&Ahi[(size_t)(m0 + r) * 128 + kc + v];
            *(s16x8*)&sm.s.A[1][r * PITCH + v] = *(const s16x8*)&Alo[(size_t)(m0 + r) * 128 + kc + v];
        }
#pragma unroll
        for (int t = 0; t < 4; ++t) {
            int i = tid + t * 256; int r = i >> 3, v = (i & 7) * 8;
            *(s16x8*)&sm.s.B[0][r * PITCH + v] = *(const s16x8*)&Bhi[r * 128 + kc + v];
            *(s16x8*)&sm.s.B[1][r * PITCH + v] = *(const s16x8*)&Blo[r * 128 + kc + v];
        }
        __syncthreads();
#pragma unroll
        for (int ks = 0; ks < 2; ++ks) {
            const int ko = ks * 32 + lk8;
            s16x8 ahi[4], alo[4], bhi[4], blo[4];
#pragma unroll
            for (int q = 0; q < 4; ++q) {
                ahi[q] = *(const s16x8*)&sm.s.A[0][(wr + q * 16 + lm) * PITCH + ko];
                alo[q] = *(const s16x8*)&sm.s.A[1][(wr + q * 16 + lm) * PITCH + ko];
                bhi[q] = *(const s16x8*)&sm.s.B[0][(wc + q * 16 + lm) * PITCH + ko];
                blo[q] = *(const s16x8*)&sm.s.B[1][(wc + q * 16 + lm) * PITCH + ko];
            }
#pragma unroll
            for (int rt = 0; rt < 4; ++rt)
#pragma unroll
                for (int ct = 0; ct < 4; ++ct) {
                    f32x4 a = acc[rt][ct];
                    a = __builtin_amdgcn_mfma_f32_16x16x32_bf16(ahi[rt], bhi[ct], a, 0, 0, 0);
                    a = __builtin_amdgcn_mfma_f32_16x16x32_bf16(ahi[rt], blo[ct], a, 0, 0, 0);
                    a = __builtin_amdgcn_mfma_f32_16x16x32_bf16(alo[rt], bhi[ct], a, 0, 0, 0);
                    acc[rt][ct] = a;
                }
        }
        __syncthreads();
    }
#pragma unroll
    for (int rt = 0; rt < 4; ++rt)
#pragma unroll
        for (int ct = 0; ct < 4; ++ct)
#pragma unroll
            for (int r = 0; r < 4; ++r)
                sm.bounce[(wr + rt * 16 + (lane >> 4) * 4 + r) * 129 + wc + ct * 16 + lm] = acc[rt][ct][r];
    __syncthreads();
    const int b = m0 >> 10, j0 = m0 & 1023;
    for (int t = 0; t < 32; ++t) {
        int i = tid + t * 256; int d = i >> 6, j2 = (i & 63) * 2;
        float x0 = sm.bounce[j2 * 129 + d], x1 = sm.bounce[(j2 + 1) * 129 + d];
        U16 h0, l0, h1, l1; splitbf(x0, h0, l0); splitbf(x1, h1, l1);
        size_t o = (((size_t)(b * 128 + d)) << 10) + j0 + j2;
        *(U32*)&Ohi[o] = (U32)h0 | ((U32)h1 << 16);
        *(U32*)&Olo[o] = (U32)l0 | ((U32)l1 << 16);
    }
}

// ---------------- K2: m = adjT @ hw per batch (2-product; adj exact) ----------------
// m97-style: glds width-16 staging, 128n x 64d tile, 512 blocks, 32 KB LDS -> 2/CU.
__global__ __launch_bounds__(256, 2) void k_adj(
    const U16* __restrict__ adjT,                                 // [NB][NN][NN] bf16
    const U16* __restrict__ hwThi, const U16* __restrict__ hwTlo, // [NB][128][1024]
    U16* __restrict__ mhi, U16* __restrict__ mlo)                 // [MTOT][128]
{
    __shared__ U16 As[128 * 64];   // 16 KB, unpadded (glds constraint)
    __shared__ U16 Bh[64 * 64];    // 8 KB
    __shared__ U16 Bl[64 * 64];    // 8 KB
    const int tid = threadIdx.x;
    const int lane = tid & 63, wv = tid >> 6;
    const int wr = (wv & 1) * 64, wcd = (wv >> 1) * 32;
    const int lm = lane & 15, lk8 = (lane >> 4) * 8, quad = lane >> 4;
    const int bi = blockIdx.x;
    const int bt = bi >> 4, tile = bi & 15;
    const int n0 = (tile >> 1) * 128, d0 = (tile & 1) * 64;

    f32x4 acc[4][2] = {};

    for (int kc = 0; kc < NN; kc += 64) {
#pragma unroll
        for (int t = 0; t < 4; ++t) {          // A: 16 KB = 1024 x 16 B
            int li = tid + t * 256;
            int r = li >> 3, sg = li & 7;
            glds16(&adjT[((size_t)bt << 20) + ((size_t)(n0 + r) << 10) + kc + sg * 8],
                   &As[li * 8]);
        }
#pragma unroll
        for (int t = 0; t < 2; ++t) {          // Bh/Bl: 8 KB each = 512 x 16 B
            int li = tid + t * 256;
            int d = li >> 3, sg = li & 7;
            size_t o = (((size_t)(bt * 128 + d0 + d)) << 10) + kc + sg * 8;
            glds16(&hwThi[o], &Bh[li * 8]);
            glds16(&hwTlo[o], &Bl[li * 8]);
        }
        __syncthreads();                       // compiler drains vmcnt before barrier
#pragma unroll
        for (int ks = 0; ks < 2; ++ks) {
            const int ko = ks * 32 + lk8;
            s16x8 a[4], bh[2], bl[2];
#pragma unroll
            for (int q = 0; q < 4; ++q)
                a[q] = *(const s16x8*)&As[(wr + q * 16 + lm) * 64 + ko];
#pragma unroll
            for (int q = 0; q < 2; ++q) {
                bh[q] = *(const s16x8*)&Bh[(wcd + q * 16 + lm) * 64 + ko];
                bl[q] = *(const s16x8*)&Bl[(wcd + q * 16 + lm) * 64 + ko];
            }
#pragma unroll
            for (int rt = 0; rt < 4; ++rt)
#pragma unroll
                for (int ct = 0; ct < 2; ++ct) {
                    f32x4 c = acc[rt][ct];
                    c = __builtin_amdgcn_mfma_f32_16x16x32_bf16(a[rt], bh[ct], c, 0, 0, 0);
                    c = __builtin_amdgcn_mfma_f32_16x16x32_bf16(a[rt], bl[ct], c, 0, 0, 0);
                    acc[rt][ct] = c;
                }
        }
        __syncthreads();
    }
    // epilogue: split + direct C-layout stores (16-lane 32 B runs)
#pragma unroll
    for (int rt = 0; rt < 4; ++rt)
#pragma unroll
        for (int ct = 0; ct < 2; ++ct)
#pragma unroll
            for (int rr = 0; rr < 4; ++rr) {
                int n = n0 + wr + rt * 16 + quad * 4 + rr;
                int d = d0 + wcd + ct * 16 + lm;
                U16 hi, lo; splitbf(acc[rt][ct][rr], hi, lo);
                size_t o = ((size_t)(bt * NN + n)) * 128 + d;
                mhi[o] = hi; mlo[o] = lo;
            }
}

// ---------------- K3 fused: gates + GRU, zero LDS, no barriers ----------------
__global__ __launch_bounds__(256, 1) void k_fused(
    const U16* __restrict__ mhi, const U16* __restrict__ mlo,    // [MTOT][128]
    const U16* __restrict__ hhi, const U16* __restrict__ hlo,    // [MTOT][128]
    const U16* __restrict__ wihhi, const U16* __restrict__ wihlo,// [384][128] layer slice
    const U16* __restrict__ whhhi, const U16* __restrict__ whhlo,
    const float* __restrict__ bih, const float* __restrict__ bhh,// [384] layer slice
    const float* __restrict__ mask,                              // [MTOT]
    U16* __restrict__ houthi, U16* __restrict__ houtlo,
    float* __restrict__ out, int last)
{
    const int tid = threadIdx.x;
    const int lane = tid & 63, wv = tid >> 6;
    const int wr = (wv & 1) * 64, wc = (wv >> 1) * 64;
    const int lm = lane & 15, lk8 = (lane >> 4) * 8, quad = lane >> 4;
    const int m0 = blockIdx.x * 128;

    f32x4 aR[4][4], aZ[4][4], aXN[4][4], aHN[4][4];
#pragma unroll
    for (int ct = 0; ct < 4; ++ct) {
        const int col = wc + ct * 16 + lm;
        const float bR  = bih[col]       + bhh[col];
        const float bZ  = bih[128 + col] + bhh[128 + col];
        const float bXN = bih[256 + col];
        const float bHN = bhh[256 + col];
#pragma unroll
        for (int rt = 0; rt < 4; ++rt) {
            aR[rt][ct]  = f32x4{bR, bR, bR, bR};
            aZ[rt][ct]  = f32x4{bZ, bZ, bZ, bZ};
            aXN[rt][ct] = f32x4{bXN, bXN, bXN, bXN};
            aHN[rt][ct] = f32x4{bHN, bHN, bHN, bHN};
        }
    }

    for (int ch = 0; ch < 4; ++ch) {
        const U16* __restrict__ Ahi = (ch < 2) ? mhi : hhi;
        const U16* __restrict__ Alo = (ch < 2) ? mlo : hlo;
        const U16* __restrict__ Whi = (ch < 2) ? wihhi : whhhi;
        const U16* __restrict__ Wlo = (ch < 2) ? wihlo : whhlo;
        const int kb = (ch & 1) * 64;
#pragma unroll
        for (int ks = 0; ks < 2; ++ks) {
            const int kg = kb + ks * 32 + lk8;
            s16x8 ahi[4], alo[4];
#pragma unroll
            for (int q = 0; q < 4; ++q) {
                size_t ao = (size_t)(m0 + wr + q * 16 + lm) * 128 + kg;
                ahi[q] = *(const s16x8*)&Ahi[ao];
                alo[q] = *(const s16x8*)&Alo[ao];
            }
#pragma unroll
            for (int ct = 0; ct < 4; ++ct) {
                const int colr = wc + ct * 16 + lm;
                s16x8 bhiR = *(const s16x8*)&Whi[(size_t)colr * 128 + kg];
                s16x8 bloR = *(const s16x8*)&Wlo[(size_t)colr * 128 + kg];
                s16x8 bhiZ = *(const s16x8*)&Whi[(size_t)(128 + colr) * 128 + kg];
                s16x8 bloZ = *(const s16x8*)&Wlo[(size_t)(128 + colr) * 128 + kg];
                s16x8 bhiN = *(const s16x8*)&Whi[(size_t)(256 + colr) * 128 + kg];
                s16x8 bloN = *(const s16x8*)&Wlo[(size_t)(256 + colr) * 128 + kg];
#pragma unroll
                for (int rt = 0; rt < 4; ++rt) {
                    f32x4 r = aR[rt][ct];
                    r = __builtin_amdgcn_mfma_f32_16x16x32_bf16(ahi[rt], bhiR, r, 0, 0, 0);
                    r = __builtin_amdgcn_mfma_f32_16x16x32_bf16(ahi[rt], bloR, r, 0, 0, 0);
                    r = __builtin_amdgcn_mfma_f32_16x16x32_bf16(alo[rt], bhiR, r, 0, 0, 0);
                    aR[rt][ct] = r;
                    f32x4 z = aZ[rt][ct];
                    z = __builtin_amdgcn_mfma_f32_16x16x32_bf16(ahi[rt], bhiZ, z, 0, 0, 0);
                    z = __builtin_amdgcn_mfma_f32_16x16x32_bf16(ahi[rt], bloZ, z, 0, 0, 0);
                    z = __builtin_amdgcn_mfma_f32_16x16x32_bf16(alo[rt], bhiZ, z, 0, 0, 0);
                    aZ[rt][ct] = z;
                }
                if (ch < 2) {
#pragma unroll
                    for (int rt = 0; rt < 4; ++rt) {
                        f32x4 n = aXN[rt][ct];
                        n = __builtin_amdgcn_mfma_f32_16x16x32_bf16(ahi[rt], bhiN, n, 0, 0, 0);
                        n = __builtin_amdgcn_mfma_f32_16x16x32_bf16(ahi[rt], bloN, n, 0, 0, 0);
                        n = __builtin_amdgcn_mfma_f32_16x16x32_bf16(alo[rt], bhiN, n, 0, 0, 0);
                        aXN[rt][ct] = n;
                    }
                } else {
#pragma unroll
                    for (int rt = 0; rt < 4; ++rt) {
                        f32x4 n = aHN[rt][ct];
                        n = __builtin_amdgcn_mfma_f32_16x16x32_bf16(ahi[rt], bhiN, n, 0, 0, 0);
                        n = __builtin_amdgcn_mfma_f32_16x16x32_bf16(ahi[rt], bloN, n, 0, 0, 0);
                        n = __builtin_amdgcn_mfma_f32_16x16x32_bf16(alo[rt], bhiN, n, 0, 0, 0);
                        aHN[rt][ct] = n;
                    }
                }
            }
        }
    }

    // GRU epilogue in-register; h re-read from global (L2-hot)
#pragma unroll
    for (int rt = 0; rt < 4; ++rt) {
#pragma unroll
        for (int ct = 0; ct < 4; ++ct) {
            const int col = wc + ct * 16 + lm;
#pragma unroll
            for (int rr = 0; rr < 4; ++rr) {
                const int row = m0 + wr + rt * 16 + quad * 4 + rr;
                float r = sigmoidf_(aR[rt][ct][rr]);
                float z = sigmoidf_(aZ[rt][ct][rr]);
                float n = tanhf(aXN[rt][ct][rr] + r * aHN[rt][ct][rr]);
                size_t ho = (size_t)row * 128 + col;
                float hv = bf2f(hhi[ho]) + bf2f(hlo[ho]);
                float hnew = (1.f - z) * n + z * hv;
                if (last) {
                    out[ho] = hnew * mask[row];
                } else {
                    U16 hi2, lo2; splitbf(hnew, hi2, lo2);
                    houthi[ho] = hi2;
                    houtlo[ho] = lo2;
                }
            }
        }
    }
}

// ---------------- prep: split/transpose weights ----------------
__global__ __launch_bounds__(256) void k_prep(
    const float* __restrict__ w, const float* __restrict__ wih, const float* __restrict__ whh,
    U16* __restrict__ wThi, U16* __restrict__ wTlo,
    U16* __restrict__ wihhi, U16* __restrict__ wihlo,
    U16* __restrict__ whhhi, U16* __restrict__ whhlo)
{
    int i = blockIdx.x * 256 + threadIdx.x;        // 458752
    if (i < 65536) {                               // weight [L][C][C] -> wT [L][d][c]
        int l = i >> 14, rem = i & 16383, c = rem >> 7, d = rem & 127;
        U16 hi, lo; splitbf(w[i], hi, lo);
        int o = (l << 14) + (d << 7) + c;
        wThi[o] = hi; wTlo[o] = lo;
    } else if (i < 262144) {                       // w_ih direct [L][384][128]
        int j = i - 65536;
        U16 hi, lo; splitbf(wih[j], hi, lo);
        wihhi[j] = hi; wihlo[j] = lo;
    } else {                                       // w_hh direct
        int j = i - 262144;
        U16 hi, lo; splitbf(whh[j], hi, lo);
        whhhi[j] = hi; whhlo[j] = lo;
    }
}

__global__ __launch_bounds__(256) void k_init(const float* __restrict__ x,
                                              U16* __restrict__ hhi, U16* __restrict__ hlo)
{
    int i = blockIdx.x * 256 + threadIdx.x;
    U16 hi, lo; splitbf(x[i], hi, lo);
    hhi[i] = hi; hlo[i] = lo;
}

// ---------------- launch ----------------
extern "C" void kernel_launch(void* const* d_in, const int* in_sizes, int n_in,
                              void* d_out, int out_size, void* d_ws, size_t ws_size,
                              hipStream_t stream) {
    (void)in_sizes; (void)n_in; (void)out_size; (void)ws_size;
    const float* x    = (const float*)d_in[0];
    const float* adj  = (const float*)d_in[1];
    const float* mask = (const float*)d_in[2];
    const float* wgt  = (const float*)d_in[3];
    const float* wih  = (const float*)d_in[4];
    const float* whh  = (const float*)d_in[5];
    const float* bih  = (const float*)d_in[6];
    const float* bhh  = (const float*)d_in[7];
    float* out = (float*)d_out;

    char* p = (char*)d_ws;
    U16* adjT    = (U16*)p;                p += (size_t)NB * NN * NN * 2;   // 67.1 MB
    U16* h_hi    = (U16*)p;                p += (size_t)MTOT * NC * 2;
    U16* h_lo    = (U16*)p;                p += (size_t)MTOT * NC * 2;
    U16* hwT_hi  = (U16*)p;                p += (size_t)NB * NC * NN * 2;
    U16* hwT_lo  = (U16*)p;                p += (size_t)NB * NC * NN * 2;
    U16* m_hi    = (U16*)p;                p += (size_t)MTOT * NC * 2;
    U16* m_lo    = (U16*)p;                p += (size_t)MTOT * NC * 2;
    U16* wT_hi   = (U16*)p;                p += (size_t)NL * NC * NC * 2;
    U16* wT_lo   = (U16*)p;                p += (size_t)NL * NC * NC * 2;
    U16* wih_hi  = (U16*)p;                p += (size_t)NL * 384 * NC * 2;
    U16* wih_lo  = (U16*)p;                p += (size_t)NL * 384 * NC * 2;
    U16* whh_hi  = (U16*)p;                p += (size_t)NL * 384 * NC * 2;
    U16* whh_lo  = (U16*)p;                p += (size_t)NL * 384 * NC * 2;

    k_prep<<<1792, 256, 0, stream>>>(wgt, wih, whh, wT_hi, wT_lo, wih_hi, wih_lo, whh_hi, whh_lo);
    k_init<<<16384, 256, 0, stream>>>(x, h_hi, h_lo);
    k_adjT<<<dim3(16, 16, NB), 256, 0, stream>>>(adj, adjT);

    for (int l = 0; l < NL; ++l) {
        k_hw<<<256, 256, 0, stream>>>(h_hi, h_lo,
                                      wT_hi + l * 16384, wT_lo + l * 16384,
                                      hwT_hi, hwT_lo);
        k_adj<<<512, 256, 0, stream>>>(adjT, hwT_hi, hwT_lo, m_hi, m_lo);
        k_fused<<<256, 256, 0, stream>>>(m_hi, m_lo, h_hi, h_lo,
                                         wih_hi + l * 49152, wih_lo + l * 49152,
                                         whh_hi + l * 49152, whh_lo + l * 49152,
                                         bih + l * 384, bhh + l * 384, mask,
                                         h_hi, h_lo, out, (l == NL - 1) ? 1 : 0);
    }
}

// Round 5
// 606.946 us; speedup vs baseline: 1.3166x; 1.0820x over previous
//
#include <hip/hip_runtime.h>
#include <stdint.h>

// DenseGGNN on MI355X, round 5 (differential fix of round-4 fusion).
//  - k_mega2: phase 1 adjT-GEMM (64n x 128d, K=1024, glds staging) -> m written to
//    GLOBAL hi/lo -> __syncthreads -> phase 2 gate GEMM reads m and h fragments from
//    GLOBAL (round-3 k_fused proven pattern) -> GRU in-register.
//    No LDS union, no h-in-LDS (round-4's unproven mechanics removed).
//  - k_setup: adjT transpose + weight split + h init (logic verbatim from round 3).
//  - 9 dispatches/call.

#define NB 32
#define NN 1024
#define NC 128
#define NL 4
#define MTOT (NB * NN)   // 32768

#define KT 64
#define PITCH 72         // k_hw LDS pitch

typedef __attribute__((ext_vector_type(8))) short s16x8;
typedef __attribute__((ext_vector_type(4))) float f32x4;
typedef __attribute__((ext_vector_type(2))) unsigned int u32x2;
typedef unsigned short U16;
typedef unsigned int U32;

__device__ __forceinline__ U16 f2bf(float f) {
    union { float f; U32 u; } v; v.f = f;
    return (U16)((v.u + 0x7FFFu + ((v.u >> 16) & 1u)) >> 16);  // RNE
}
__device__ __forceinline__ float bf2f(U16 h) {
    union { U32 u; float f; } v; v.u = ((U32)h) << 16;
    return v.f;
}
__device__ __forceinline__ void splitbf(float x, U16& hi, U16& lo) {
    hi = f2bf(x);
    lo = f2bf(x - bf2f(hi));
}
__device__ __forceinline__ float sigmoidf_(float x) { return 1.f / (1.f + __expf(-x)); }

__device__ __forceinline__ void glds16(const void* g, void* l) {
    __builtin_amdgcn_global_load_lds(
        (const __attribute__((address_space(1))) void*)g,
        (__attribute__((address_space(3))) void*)l, 16, 0, 0);
}

// ---------------- setup: adjT transpose + weight split + h init ----------------
__global__ __launch_bounds__(256) void k_setup(
    const float* __restrict__ adj, U16* __restrict__ adjT,
    const float* __restrict__ w, const float* __restrict__ wih, const float* __restrict__ whh,
    U16* __restrict__ wThi, U16* __restrict__ wTlo,
    U16* __restrict__ wihhi, U16* __restrict__ wihlo,
    U16* __restrict__ whhhi, U16* __restrict__ whhlo,
    const float* __restrict__ x, U16* __restrict__ hhi, U16* __restrict__ hlo)
{
    __shared__ float t[64 * 65];
    const int bid = blockIdx.x, tid = threadIdx.x;
    if (bid < 8192) {                              // adj fp32 [b][j][n] -> adjT bf16 [b][n][j]
        const int b = bid >> 8, rem = bid & 255;
        const int j0 = (rem & 15) * 64, n0 = (rem >> 4) * 64;
        const int rr = tid >> 4, c4 = (tid & 15) * 4;
#pragma unroll
        for (int p = 0; p < 4; ++p) {
            int j = p * 16 + rr;
            f32x4 v = *(const f32x4*)&adj[((size_t)b << 20) + ((size_t)(j0 + j) << 10) + n0 + c4];
#pragma unroll
            for (int u = 0; u < 4; ++u) t[j * 65 + c4 + u] = v[u];
        }
        __syncthreads();
#pragma unroll
        for (int p = 0; p < 4; ++p) {
            int n = p * 16 + rr;
            U16 h0 = f2bf(t[(c4 + 0) * 65 + n]);
            U16 h1 = f2bf(t[(c4 + 1) * 65 + n]);
            U16 h2 = f2bf(t[(c4 + 2) * 65 + n]);
            U16 h3 = f2bf(t[(c4 + 3) * 65 + n]);
            u32x2 pk; pk[0] = (U32)h0 | ((U32)h1 << 16); pk[1] = (U32)h2 | ((U32)h3 << 16);
            *(u32x2*)&adjT[((size_t)b << 20) + ((size_t)(n0 + n) << 10) + j0 + c4] = pk;
        }
    } else if (bid < 9984) {                       // weight split (458752 elements)
        int i = (bid - 8192) * 256 + tid;
        if (i < 65536) {                           // weight [L][C][C] -> wT [L][d][c]
            int l = i >> 14, rem = i & 16383, c = rem >> 7, d = rem & 127;
            U16 hi, lo; splitbf(w[i], hi, lo);
            int o = (l << 14) + (d << 7) + c;
            wThi[o] = hi; wTlo[o] = lo;
        } else if (i < 262144) {
            int j = i - 65536;
            U16 hi, lo; splitbf(wih[j], hi, lo);
            wihhi[j] = hi; wihlo[j] = lo;
        } else {
            int j = i - 262144;
            U16 hi, lo; splitbf(whh[j], hi, lo);
            whhhi[j] = hi; whhlo[j] = lo;
        }
    } else {                                       // h init from x (4.19M elements)
        int base = (bid - 9984) * 2048 + tid;
#pragma unroll
        for (int p = 0; p < 8; ++p) {
            int i = base + p * 256;
            U16 hi, lo; splitbf(x[i], hi, lo);
            hhi[i] = hi; hlo[i] = lo;
        }
    }
}

// ---------------- K1: hw = h @ W (3-product), writes hwT[b][d][j] hi/lo ----------------
struct __align__(16) Smem3 {
    union {
        struct { U16 A[2][128 * PITCH]; U16 B[2][128 * PITCH]; } s;   // 73728 B
        float bounce[128 * 129];                                      // 66048 B
    };
};

__global__ __launch_bounds__(256, 2) void k_hw(
    const U16* __restrict__ Ahi, const U16* __restrict__ Alo,
    const U16* __restrict__ Bhi, const U16* __restrict__ Blo,
    U16* __restrict__ Ohi, U16* __restrict__ Olo)
{
    __shared__ Smem3 sm;
    const int tid = threadIdx.x;
    const int lane = tid & 63, wv = tid >> 6;
    const int wr = (wv & 1) * 64, wc = (wv >> 1) * 64;
    const int lm = lane & 15, lk8 = (lane >> 4) * 8;
    const int m0 = blockIdx.x * 128;

    f32x4 acc[4][4] = {};

    for (int kc = 0; kc < 128; kc += KT) {
#pragma unroll
        for (int t = 0; t < 4; ++t) {
            int i = tid + t * 256; int r = i >> 3, v = (i & 7) * 8;
            *(s16x8*)&sm.s.A[0][r * PITCH + v] = *(const s16x8*)&Ahi[(size_t)(m0 + r) * 128 + kc + v];
            *(s16x8*)&sm.s.A[1][r * PITCH + v] = *(const s16x8*)&Alo[(size_t)(m0 + r) * 128 + kc + v];
        }
#pragma unroll
        for (int t = 0; t < 4; ++t) {
            int i = tid + t * 256; int r = i >> 3, v = (i & 7) * 8;
            *(s16x8*)&sm.s.B[0][r * PITCH + v] = *(const s16x8*)&Bhi[r * 128 + kc + v];
            *(s16x8*)&sm.s.B[1][r * PITCH + v] = *(const s16x8*)&Blo[r * 128 + kc + v];
        }
        __syncthreads();
#pragma unroll
        for (int ks = 0; ks < 2; ++ks) {
            const int ko = ks * 32 + lk8;
            s16x8 ahi[4], alo[4], bhi[4], blo[4];
#pragma unroll
            for (int q = 0; q < 4; ++q) {
                ahi[q] = *(const s16x8*)&sm.s.A[0][(wr + q * 16 + lm) * PITCH + ko];
                alo[q] = *(const s16x8*)&sm.s.A[1][(wr + q * 16 + lm) * PITCH + ko];
                bhi[q] = *(const s16x8*)&sm.s.B[0][(wc + q * 16 + lm) * PITCH + ko];
                blo[q] = *(const s16x8*)&sm.s.B[1][(wc + q * 16 + lm) * PITCH + ko];
            }
#pragma unroll
            for (int rt = 0; rt < 4; ++rt)
#pragma unroll
                for (int ct = 0; ct < 4; ++ct) {
                    f32x4 a = acc[rt][ct];
                    a = __builtin_amdgcn_mfma_f32_16x16x32_bf16(ahi[rt], bhi[ct], a, 0, 0, 0);
                    a = __builtin_amdgcn_mfma_f32_16x16x32_bf16(ahi[rt], blo[ct], a, 0, 0, 0);
                    a = __builtin_amdgcn_mfma_f32_16x16x32_bf16(alo[rt], bhi[ct], a, 0, 0, 0);
                    acc[rt][ct] = a;
                }
        }
        __syncthreads();
    }
#pragma unroll
    for (int rt = 0; rt < 4; ++rt)
#pragma unroll
        for (int ct = 0; ct < 4; ++ct)
#pragma unroll
            for (int r = 0; r < 4; ++r)
                sm.bounce[(wr + rt * 16 + (lane >> 4) * 4 + r) * 129 + wc + ct * 16 + lm] = acc[rt][ct][r];
    __syncthreads();
    const int b = m0 >> 10, j0 = m0 & 1023;
    for (int t = 0; t < 32; ++t) {
        int i = tid + t * 256; int d = i >> 6, j2 = (i & 63) * 2;
        float x0 = sm.bounce[j2 * 129 + d], x1 = sm.bounce[(j2 + 1) * 129 + d];
        U16 h0, l0, h1, l1; splitbf(x0, h0, l0); splitbf(x1, h1, l1);
        size_t o = (((size_t)(b * 128 + d)) << 10) + j0 + j2;
        *(U32*)&Ohi[o] = (U32)h0 | ((U32)h1 << 16);
        *(U32*)&Olo[o] = (U32)l0 | ((U32)l1 << 16);
    }
}

// ---------------- k_mega2: adjT-GEMM -> m (global) -> gates -> GRU, 64-row blocks ----------------
__global__ __launch_bounds__(256, 2) void k_mega2(
    const U16* __restrict__ adjT,                                 // [NB][NN][NN]
    const U16* __restrict__ hwThi, const U16* __restrict__ hwTlo, // [NB][128][1024]
    U16* mhi, U16* mlo,                                           // [MTOT][128] scratch (no restrict: W->R)
    const U16* __restrict__ hhi, const U16* __restrict__ hlo,     // [MTOT][128]
    const U16* __restrict__ wihhi, const U16* __restrict__ wihlo, // [384][128] layer slice
    const U16* __restrict__ whhhi, const U16* __restrict__ whhlo,
    const float* __restrict__ bih, const float* __restrict__ bhh, // [384] layer slice
    const float* __restrict__ mask,
    U16* __restrict__ houthi, U16* __restrict__ houtlo,
    float* __restrict__ out, int last)
{
    __shared__ U16 As[64 * 64];    // 8 KB (glds: unpadded, lane-consecutive)
    __shared__ U16 Bh[128 * 64];   // 16 KB
    __shared__ U16 Bl[128 * 64];   // 16 KB
    const int tid = threadIdx.x;
    const int lane = tid & 63, wv = tid >> 6;
    const int wd0 = wv * 32;                       // wave's 32-col slice (d / gate-col)
    const int lm = lane & 15, lk8 = (lane >> 4) * 8, quad = lane >> 4;
    const int bt = blockIdx.x >> 4;
    const int n0 = (blockIdx.x & 15) * 64;
    const int row0 = bt * NN + n0;

    // ---- phase 1: m = adjT @ hw (2-product; adj exact bf16) ----
    f32x4 macc[4][2] = {};
    for (int kc = 0; kc < NN; kc += 64) {
#pragma unroll
        for (int t = 0; t < 2; ++t) {              // As: 64 rows x 64 k
            int li = tid + t * 256; int r = li >> 3, sg = li & 7;
            glds16(&adjT[((size_t)bt << 20) + ((size_t)(n0 + r) << 10) + kc + sg * 8],
                   &As[li * 8]);
        }
#pragma unroll
        for (int t = 0; t < 4; ++t) {              // Bh/Bl: 128 d-rows x 64 k
            int li = tid + t * 256; int d = li >> 3, sg = li & 7;
            size_t o = (((size_t)(bt * 128 + d)) << 10) + kc + sg * 8;
            glds16(&hwThi[o], &Bh[li * 8]);
            glds16(&hwTlo[o], &Bl[li * 8]);
        }
        __syncthreads();
#pragma unroll
        for (int ks = 0; ks < 2; ++ks) {
            const int ko = ks * 32 + lk8;
            s16x8 a[4], bh[2], bl[2];
#pragma unroll
            for (int q = 0; q < 4; ++q)
                a[q] = *(const s16x8*)&As[(q * 16 + lm) * 64 + ko];
#pragma unroll
            for (int q = 0; q < 2; ++q) {
                bh[q] = *(const s16x8*)&Bh[(wd0 + q * 16 + lm) * 64 + ko];
                bl[q] = *(const s16x8*)&Bl[(wd0 + q * 16 + lm) * 64 + ko];
            }
#pragma unroll
            for (int rt = 0; rt < 4; ++rt)
#pragma unroll
                for (int ct = 0; ct < 2; ++ct) {
                    f32x4 c = macc[rt][ct];
                    c = __builtin_amdgcn_mfma_f32_16x16x32_bf16(a[rt], bh[ct], c, 0, 0, 0);
                    c = __builtin_amdgcn_mfma_f32_16x16x32_bf16(a[rt], bl[ct], c, 0, 0, 0);
                    macc[rt][ct] = c;
                }
        }
        __syncthreads();
    }

    // ---- m -> global hi/lo (block owns complete rows; re-read below after barrier) ----
#pragma unroll
    for (int rt = 0; rt < 4; ++rt)
#pragma unroll
        for (int ct = 0; ct < 2; ++ct)
#pragma unroll
            for (int rr = 0; rr < 4; ++rr) {
                int rloc = rt * 16 + quad * 4 + rr;
                int d = wd0 + ct * 16 + lm;
                U16 hi, lo; splitbf(macc[rt][ct][rr], hi, lo);
                size_t o = (size_t)(row0 + rloc) * 128 + d;
                mhi[o] = hi; mlo[o] = lo;
            }
    __syncthreads();                               // drain stores; other waves' m visible

    // ---- phase 2: gates (K=256 concat [m|h], 3-product) + GRU, fragments from global ----
    f32x4 aR[4][2], aZ[4][2], aXN[4][2], aHN[4][2];
#pragma unroll
    for (int ct = 0; ct < 2; ++ct) {
        const int col = wd0 + ct * 16 + lm;
        const float bR  = bih[col]       + bhh[col];
        const float bZ  = bih[128 + col] + bhh[128 + col];
        const float bXN = bih[256 + col];
        const float bHN = bhh[256 + col];
#pragma unroll
        for (int rt = 0; rt < 4; ++rt) {
            aR[rt][ct]  = f32x4{bR, bR, bR, bR};
            aZ[rt][ct]  = f32x4{bZ, bZ, bZ, bZ};
            aXN[rt][ct] = f32x4{bXN, bXN, bXN, bXN};
            aHN[rt][ct] = f32x4{bHN, bHN, bHN, bHN};
        }
    }

    for (int ch = 0; ch < 4; ++ch) {
        const U16* Ahi = (ch < 2) ? (const U16*)mhi : hhi;
        const U16* Alo = (ch < 2) ? (const U16*)mlo : hlo;
        const U16* __restrict__ Whi = (ch < 2) ? wihhi : whhhi;
        const U16* __restrict__ Wlo = (ch < 2) ? wihlo : whhlo;
        const int kb = (ch & 1) * 64;
#pragma unroll
        for (int ks = 0; ks < 2; ++ks) {
            const int ko = kb + ks * 32 + lk8;     // k within [0,128)
            s16x8 ahi[4], alo[4];
#pragma unroll
            for (int q = 0; q < 4; ++q) {
                size_t ao = (size_t)(row0 + q * 16 + lm) * 128 + ko;
                ahi[q] = *(const s16x8*)&Ahi[ao];
                alo[q] = *(const s16x8*)&Alo[ao];
            }
#pragma unroll
            for (int ct = 0; ct < 2; ++ct) {
                const int col = wd0 + ct * 16 + lm;
                s16x8 bhiR = *(const s16x8*)&Whi[(size_t)col * 128 + ko];
                s16x8 bloR = *(const s16x8*)&Wlo[(size_t)col * 128 + ko];
                s16x8 bhiZ = *(const s16x8*)&Whi[(size_t)(128 + col) * 128 + ko];
                s16x8 bloZ = *(const s16x8*)&Wlo[(size_t)(128 + col) * 128 + ko];
                s16x8 bhiN = *(const s16x8*)&Whi[(size_t)(256 + col) * 128 + ko];
                s16x8 bloN = *(const s16x8*)&Wlo[(size_t)(256 + col) * 128 + ko];
#pragma unroll
                for (int rt = 0; rt < 4; ++rt) {
                    f32x4 r = aR[rt][ct];
                    r = __builtin_amdgcn_mfma_f32_16x16x32_bf16(ahi[rt], bhiR, r, 0, 0, 0);
                    r = __builtin_amdgcn_mfma_f32_16x16x32_bf16(ahi[rt], bloR, r, 0, 0, 0);
                    r = __builtin_amdgcn_mfma_f32_16x16x32_bf16(alo[rt], bhiR, r, 0, 0, 0);
                    aR[rt][ct] = r;
                    f32x4 z = aZ[rt][ct];
                    z = __builtin_amdgcn_mfma_f32_16x16x32_bf16(ahi[rt], bhiZ, z, 0, 0, 0);
                    z = __builtin_amdgcn_mfma_f32_16x16x32_bf16(ahi[rt], bloZ, z, 0, 0, 0);
                    z = __builtin_amdgcn_mfma_f32_16x16x32_bf16(alo[rt], bhiZ, z, 0, 0, 0);
                    aZ[rt][ct] = z;
                }
                if (ch < 2) {
#pragma unroll
                    for (int rt = 0; rt < 4; ++rt) {
                        f32x4 n = aXN[rt][ct];
                        n = __builtin_amdgcn_mfma_f32_16x16x32_bf16(ahi[rt], bhiN, n, 0, 0, 0);
                        n = __builtin_amdgcn_mfma_f32_16x16x32_bf16(ahi[rt], bloN, n, 0, 0, 0);
                        n = __builtin_amdgcn_mfma_f32_16x16x32_bf16(alo[rt], bhiN, n, 0, 0, 0);
                        aXN[rt][ct] = n;
                    }
                } else {
#pragma unroll
                    for (int rt = 0; rt < 4; ++rt) {
                        f32x4 n = aHN[rt][ct];
                        n = __builtin_amdgcn_mfma_f32_16x16x32_bf16(ahi[rt], bhiN, n, 0, 0, 0);
                        n = __builtin_amdgcn_mfma_f32_16x16x32_bf16(ahi[rt], bloN, n, 0, 0, 0);
                        n = __builtin_amdgcn_mfma_f32_16x16x32_bf16(alo[rt], bhiN, n, 0, 0, 0);
                        aHN[rt][ct] = n;
                    }
                }
            }
        }
    }

    // ---- GRU epilogue; h re-read from global (round-3 proven); in-place h update ----
#pragma unroll
    for (int rt = 0; rt < 4; ++rt) {
#pragma unroll
        for (int ct = 0; ct < 2; ++ct) {
            const int col = wd0 + ct * 16 + lm;
#pragma unroll
            for (int rr = 0; rr < 4; ++rr) {
                const int row = row0 + rt * 16 + quad * 4 + rr;
                float r = sigmoidf_(aR[rt][ct][rr]);
                float z = sigmoidf_(aZ[rt][ct][rr]);
                float n = tanhf(aXN[rt][ct][rr] + r * aHN[rt][ct][rr]);
                size_t ho = (size_t)row * 128 + col;
                float hv = bf2f(hhi[ho]) + bf2f(hlo[ho]);
                float hnew = (1.f - z) * n + z * hv;
                if (last) {
                    out[ho] = hnew * mask[row];
                } else {
                    U16 hi2, lo2; splitbf(hnew, hi2, lo2);
                    houthi[ho] = hi2;
                    houtlo[ho] = lo2;
                }
            }
        }
    }
}

// ---------------- launch ----------------
extern "C" void kernel_launch(void* const* d_in, const int* in_sizes, int n_in,
                              void* d_out, int out_size, void* d_ws, size_t ws_size,
                              hipStream_t stream) {
    (void)in_sizes; (void)n_in; (void)out_size; (void)ws_size;
    const float* x    = (const float*)d_in[0];
    const float* adj  = (const float*)d_in[1];
    const float* mask = (const float*)d_in[2];
    const float* wgt  = (const float*)d_in[3];
    const float* wih  = (const float*)d_in[4];
    const float* whh  = (const float*)d_in[5];
    const float* bih  = (const float*)d_in[6];
    const float* bhh  = (const float*)d_in[7];
    float* out = (float*)d_out;

    char* p = (char*)d_ws;
    U16* adjT    = (U16*)p;                p += (size_t)NB * NN * NN * 2;   // 67.1 MB
    U16* h_hi    = (U16*)p;                p += (size_t)MTOT * NC * 2;
    U16* h_lo    = (U16*)p;                p += (size_t)MTOT * NC * 2;
    U16* hwT_hi  = (U16*)p;                p += (size_t)NB * NC * NN * 2;
    U16* hwT_lo  = (U16*)p;                p += (size_t)NB * NC * NN * 2;
    U16* m_hi    = (U16*)p;                p += (size_t)MTOT * NC * 2;
    U16* m_lo    = (U16*)p;                p += (size_t)MTOT * NC * 2;
    U16* wT_hi   = (U16*)p;                p += (size_t)NL * NC * NC * 2;
    U16* wT_lo   = (U16*)p;                p += (size_t)NL * NC * NC * 2;
    U16* wih_hi  = (U16*)p;                p += (size_t)NL * 384 * NC * 2;
    U16* wih_lo  = (U16*)p;                p += (size_t)NL * 384 * NC * 2;
    U16* whh_hi  = (U16*)p;                p += (size_t)NL * 384 * NC * 2;
    U16* whh_lo  = (U16*)p;                p += (size_t)NL * 384 * NC * 2;

    k_setup<<<12032, 256, 0, stream>>>(adj, adjT, wgt, wih, whh,
                                       wT_hi, wT_lo, wih_hi, wih_lo, whh_hi, whh_lo,
                                       x, h_hi, h_lo);

    for (int l = 0; l < NL; ++l) {
        k_hw<<<256, 256, 0, stream>>>(h_hi, h_lo,
                                      wT_hi + l * 16384, wT_lo + l * 16384,
                                      hwT_hi, hwT_lo);
        k_mega2<<<512, 256, 0, stream>>>(adjT, hwT_hi, hwT_lo, m_hi, m_lo, h_hi, h_lo,
                                         wih_hi + l * 49152, wih_lo + l * 49152,
                                         whh_hi + l * 49152, whh_lo + l * 49152,
                                         bih + l * 384, bhh + l * 384, mask,
                                         h_hi, h_lo, out, (l == NL - 1) ? 1 : 0);
    }
}